// Round 11
// baseline (2124.380 us; speedup 1.0000x reference)
//
#include <hip/hip_runtime.h>

// LSTM recurrence, 50 steps. B=2048, T=50, F=256, H=256, gates i,f,g,o.
// Phase 0: pack W,U (fp32) -> bf16 in MFMA-fragment order (W2, U2).
// Phase 1: xz = x@W + b for ALL timesteps (parallel GEMM), bf16 frag layout.
// Phase 2: ONE persistent kernel, 128 blocks x 16 batch rows. ALL of U lives
//          in AGPRs: 8 panels x 8 frags x short8 = 256 AGPR/thread = 512 KB
//          per block. gfx950 MFMA reads B directly from AGPR; "+a" asm
//          touches inside the loop make the panels loop-carried opaque AGPR
//          defs -- non-rematerializable, and in a register class the VALU
//          code never pressures (rounds 5-10: every VGPR-resident plan got
//          remat'd back to per-step L2 streams, VGPR_Count stuck at 128,
//          ~7us/step of L2 ingress). Per-step VMEM = one 64B XZ prefetch.
//          h dbuf in LDS (16 KB total), one lgkm-only barrier per step.

#define B_ 2048
#define T_ 50
#define F_ 256
#define H_ 256
#define NZ 1024      // 4H

typedef __attribute__((ext_vector_type(8))) short short8;
typedef __attribute__((ext_vector_type(4))) float f32x4;
typedef unsigned short ushort_t;
typedef unsigned int uint_t;

__device__ __forceinline__ ushort_t f2bf(float f) {
    uint_t u = __float_as_uint(f);
    return (ushort_t)((u + 0x7FFFu + ((u >> 16) & 1u)) >> 16);
}
__device__ __forceinline__ uint_t pack2bf(float lo, float hi) {
    return (uint_t)f2bf(lo) | ((uint_t)f2bf(hi) << 16);
}
__device__ __forceinline__ float bf2f(ushort_t u) {
    return __uint_as_float(((uint_t)u) << 16);
}
__device__ __forceinline__ float sigm(float z) {
    return __builtin_amdgcn_rcpf(1.0f + __builtin_amdgcn_exp2f(z * -1.44269504f));
}
__device__ __forceinline__ float tanh_f(float z) {
    return 2.0f * __builtin_amdgcn_rcpf(1.0f + __builtin_amdgcn_exp2f(z * -2.88539008f)) - 1.0f;
}
__device__ __forceinline__ float xz_at(uint2 u, int j) {
    uint_t v = (j < 2) ? u.x : u.y;
    v = (j & 1) ? (v >> 16) : (v & 0xFFFFu);
    return bf2f((ushort_t)v);
}

// -------- pack: fp32 [256][1024] -> bf16 frag-order panels ----------------
__global__ void pack_wu(const float* __restrict__ Wm, const float* __restrict__ Um,
                        ushort_t* __restrict__ W2, ushort_t* __restrict__ U2) {
    int gid  = blockIdx.x * 256 + threadIdx.x;   // 65536 total
    int lane = gid & 63;
    int nf   = (gid >> 6) & 7;
    int w    = (gid >> 9) & 7;
    int kf   = (gid >> 12) & 7;
    int mat  = gid >> 15;
    const float* src = mat ? Um : Wm;
    ushort_t* dst    = mat ? U2 : W2;
    int col = (nf >> 1) * 256 + w * 32 + (nf & 1) * 16 + (lane & 15);
    int kb  = kf * 32 + (lane >> 4) * 8;
    short8 v;
#pragma unroll
    for (int e = 0; e < 8; ++e)
        v[e] = (short)f2bf(src[(size_t)(kb + e) * NZ + col]);
    *(short8*)(dst + ((((size_t)kf * 8 + w) * 8 + nf) * 64 + lane) * 8) = v;
}

// -------- phase 1: xz[t] = x[:,t,:] @ W + b  (bf16, frag layout) ----------
__global__ __launch_bounds__(512, 2) void xw_gemm(
    const float* __restrict__ x, const float* __restrict__ bias,
    const ushort_t* __restrict__ W2, ushort_t* __restrict__ xz2) {
    __shared__ __align__(16) ushort_t As[32 * 256];   // 16 KB, swizzled

    const int tid = threadIdx.x;
    const int t = blockIdx.x, rb = blockIdx.y, row0 = rb * 32;
    const int w = tid >> 6, lane = tid & 63, r16 = lane & 15, q = lane >> 4;

    {
        int sr = tid >> 4, sc = tid & 15;
        const float* xp = x + ((size_t)(row0 + sr) * T_ + t) * F_ + sc * 16;
        float4 f0 = *(const float4*)(xp + 0);
        float4 f1 = *(const float4*)(xp + 4);
        float4 f2 = *(const float4*)(xp + 8);
        float4 f3 = *(const float4*)(xp + 12);
        uint4 u0 = {pack2bf(f0.x, f0.y), pack2bf(f0.z, f0.w),
                    pack2bf(f1.x, f1.y), pack2bf(f1.z, f1.w)};
        uint4 u1 = {pack2bf(f2.x, f2.y), pack2bf(f2.z, f2.w),
                    pack2bf(f3.x, f3.y), pack2bf(f3.z, f3.w)};
        int c0 = (2 * sc) ^ (sr & 7), c1 = (2 * sc + 1) ^ (sr & 7);
        *(uint4*)&As[sr * 256 + c0 * 8] = u0;
        *(uint4*)&As[sr * 256 + c1 * 8] = u1;
    }
    float bcol[8];
#pragma unroll
    for (int nf = 0; nf < 8; ++nf)
        bcol[nf] = bias[(nf >> 1) * 256 + w * 32 + (nf & 1) * 16 + r16];
    __syncthreads();

    f32x4 acc0[8], acc1[8];
#pragma unroll
    for (int nf = 0; nf < 8; ++nf) {
        acc0[nf] = (f32x4){0.f, 0.f, 0.f, 0.f};
        acc1[nf] = (f32x4){0.f, 0.f, 0.f, 0.f};
    }
    short8 SB0[8], SB1[8];

#define LOADB(BUF, KF_)                                                       \
    _Pragma("unroll") for (int nf = 0; nf < 8; ++nf)                          \
        BUF[nf] = *(const short8*)(W2 +                                       \
            ((((size_t)(KF_) * 8 + w) * 8 + nf) * 64 + lane) * 8);

#define MF1(BUF, KF_)                                                         \
    do {                                                                      \
        short8 a0_ = *(const short8*)&As[r16 * 256 + (((KF_)*4 + q) ^ (r16 & 7)) * 8];       \
        short8 a1_ = *(const short8*)&As[(16 + r16) * 256 + (((KF_)*4 + q) ^ (r16 & 7)) * 8];\
        _Pragma("unroll") for (int nf = 0; nf < 8; ++nf) {                    \
            acc0[nf] = __builtin_amdgcn_mfma_f32_16x16x32_bf16(a0_, BUF[nf], acc0[nf], 0, 0, 0); \
            acc1[nf] = __builtin_amdgcn_mfma_f32_16x16x32_bf16(a1_, BUF[nf], acc1[nf], 0, 0, 0); \
        }                                                                     \
    } while (0)

    LOADB(SB0, 0); LOADB(SB1, 1);
    MF1(SB0, 0); LOADB(SB0, 2);
    MF1(SB1, 1); LOADB(SB1, 3);
    MF1(SB0, 2); LOADB(SB0, 4);
    MF1(SB1, 3); LOADB(SB1, 5);
    MF1(SB0, 4); LOADB(SB0, 6);
    MF1(SB1, 5); LOADB(SB1, 7);
    MF1(SB0, 6);
    MF1(SB1, 7);

    uint2* outp = (uint2*)xz2;
    const size_t cb = (((size_t)t * 64 + rb) * 8 + w) * 16;
#pragma unroll
    for (int m = 0; m < 2; ++m) {
#pragma unroll
        for (int nf = 0; nf < 8; ++nf) {
            f32x4 a = m ? acc1[nf] : acc0[nf];
            float b = bcol[nf];
            uint2 o = {pack2bf(a[0] + b, a[1] + b), pack2bf(a[2] + b, a[3] + b)};
            outp[(cb + m * 8 + nf) * 64 + lane] = o;
        }
    }
#undef LOADB
#undef MF1
}

// -------- phase 2: persistent recurrence, U fully AGPR-resident -----------
__global__ __launch_bounds__(512, 1) void lstm_rec(
    const ushort_t* __restrict__ U2, const ushort_t* __restrict__ xz2,
    float* __restrict__ outp, int T) {
    __shared__ __align__(16) ushort_t hb[2][16 * 256];  // h dbuf (2 x 8 KB)

    const int tid = threadIdx.x;
    const int rb = blockIdx.x, row0 = rb * 16;
    const int w = tid >> 6, lane = tid & 63, r16 = lane & 15, q = lane >> 4;

    // h0 = 0 (buffer 0 only)
    *(uint4*)&hb[0][tid * 8] = (uint4){0, 0, 0, 0};

#define AFRAG(HP_, KF_)                                                       \
    (*(const short8*)&(HP_)[r16 * 256 + (((KF_)*4 + q) ^ (r16 & 7)) * 8])

    // ---- one-time: all 8 U panels -> AGPRs (256/thread = 512 KB/block) ----
    short8 UP[8][8];
#pragma unroll
    for (int kf = 0; kf < 8; ++kf)
#pragma unroll
        for (int nf = 0; nf < 8; ++nf)
            UP[kf][nf] = *(const short8*)(U2 +
                ((((size_t)kf * 8 + w) * 8 + nf) * 64 + lane) * 8);
    // force AGPR placement
#pragma unroll
    for (int kf = 0; kf < 8; ++kf)
#pragma unroll
        for (int nf = 0; nf < 8; ++nf)
            asm volatile("" : "+a"(UP[kf][nf]));

    const uint2* xzp = (const uint2*)xz2;
    const size_t cbconst = (((size_t)(rb >> 1)) * 8 + w) * 16 + (size_t)(rb & 1) * 8;
    const uint2* xzb = xzp + cbconst * 64 + lane;
    const size_t TSTRIDE = (size_t)8192 * 64;   // per-t stride in uint2

    f32x4 acc[8];
    f32x4 creg[2];
    creg[0] = (f32x4){0.f, 0.f, 0.f, 0.f};
    creg[1] = (f32x4){0.f, 0.f, 0.f, 0.f};

    // XZ for t=0 (steady state: loaded one full step ahead)
    uint2 XZ[8];
#pragma unroll
    for (int k = 0; k < 8; ++k) XZ[k] = xzb[(size_t)k * 64];

    int cur = 0;
    __syncthreads();   // hb[0] ready

#pragma clang loop unroll(disable)
    for (int t = 0; t < T; ++t) {
        const ushort_t* hc = hb[cur];
        ushort_t* hn = hb[cur ^ 1];

        // loop-carried AGPR pins: opaque defs, non-rematerializable
#pragma unroll
        for (int kf = 0; kf < 8; ++kf)
#pragma unroll
            for (int nf = 0; nf < 8; ++nf)
                asm volatile("" : "+a"(UP[kf][nf]));

#pragma unroll
        for (int nf = 0; nf < 8; ++nf) acc[nf] = (f32x4){0.f, 0.f, 0.f, 0.f};

        __builtin_amdgcn_s_setprio(1);
#pragma unroll
        for (int kf = 0; kf < 8; ++kf) {
            short8 a_ = AFRAG(hc, kf);
#pragma unroll
            for (int nf = 0; nf < 8; ++nf)
                acc[nf] = __builtin_amdgcn_mfma_f32_16x16x32_bf16(
                    a_, UP[kf][nf], acc[nf], 0, 0, 0);
        }
        __builtin_amdgcn_s_setprio(0);

        // epilogue: consume XZ(t), gates, cell update, h -> other LDS buffer
#pragma unroll
        for (int hf = 0; hf < 2; ++hf) {
#pragma unroll
            for (int j = 0; j < 4; ++j) {
                float zi = acc[0 + hf][j] + xz_at(XZ[0 + hf], j);
                float zf = acc[2 + hf][j] + xz_at(XZ[2 + hf], j);
                float zg = acc[4 + hf][j] + xz_at(XZ[4 + hf], j);
                float zo = acc[6 + hf][j] + xz_at(XZ[6 + hf], j);
                float ig = sigm(zi);
                float fg = sigm(zf);
                float gg = tanh_f(zg);
                float og = sigm(zo);
                float cn = fg * creg[hf][j] + ig * gg;
                float hv = og * tanh_f(cn);
                creg[hf][j] = cn;
                int row = q * 4 + j;
                int hcol = w * 32 + hf * 16 + r16;
                int chunk = (hcol >> 3) ^ (row & 7);
                hn[row * 256 + chunk * 8 + (hcol & 7)] = f2bf(hv);
            }
        }

        // XZ(t+1): one full step of cover; t=T-1 reads one tile past xz2 --
        // inside the 400MiB ws, values unused.
        {
            const uint2* xznext = xzb + (size_t)(t + 1) * TSTRIDE;
#pragma unroll
            for (int k = 0; k < 8; ++k) XZ[k] = xznext[(size_t)k * 64];
        }

        // raw barrier: drain LDS writes only; XZ global loads stay in flight.
        asm volatile("s_waitcnt lgkmcnt(0)" ::: "memory");
        __builtin_amdgcn_s_barrier();
        cur ^= 1;
    }

    // final output: each thread reads back its OWN hb writes
#pragma unroll
    for (int hf = 0; hf < 2; ++hf) {
#pragma unroll
        for (int j = 0; j < 4; ++j) {
            int row = q * 4 + j;
            int hcol = w * 32 + hf * 16 + r16;
            int chunk = (hcol >> 3) ^ (row & 7);
            float hv = bf2f(hb[cur][row * 256 + chunk * 8 + (hcol & 7)]);
            size_t oi = (size_t)(row0 + row) * H_ + hcol;
            outp[oi] = hv;
            outp[(size_t)B_ * H_ + oi] = creg[hf][j];
        }
    }
#undef AFRAG
}

extern "C" void kernel_launch(void* const* d_in, const int* in_sizes, int n_in,
                              void* d_out, int out_size, void* d_ws, size_t ws_size,
                              hipStream_t stream) {
    const float* x    = (const float*)d_in[0];
    const float* Wm   = (const float*)d_in[1];
    const float* Um   = (const float*)d_in[2];
    const float* bias = (const float*)d_in[3];

    // ws: W2 (512 KB) | U2 (512 KB) | xz2 (210 MB)   (ws_size = 400 MiB)
    ushort_t* W2  = (ushort_t*)d_ws;
    ushort_t* U2  = W2 + 262144;
    ushort_t* xz2 = U2 + 262144;

    pack_wu<<<256, 256, 0, stream>>>(Wm, Um, W2, U2);
    dim3 g1(T_, 64);
    xw_gemm<<<g1, 512, 0, stream>>>(x, bias, W2, xz2);
    lstm_rec<<<128, 512, 0, stream>>>(U2, xz2, (float*)d_out, T_);
}

// Round 13
// 589.246 us; speedup vs baseline: 3.6053x; 3.6053x over previous
//
#include <hip/hip_runtime.h>

// LSTM recurrence, 50 steps. B=2048, T=50, F=256, H=256, gates i,f,g,o.
// Phase 0: pack W,U (fp32) -> bf16 in MFMA-fragment order (W2, U2).
// Phase 1: xz = x@W + b for ALL timesteps (parallel GEMM), bf16 frag layout.
// Phase 2: 256 blocks = 32 row-groups (64 rows) x 8 col-groups (32 h-cols).
//          U-slice 64KB LDS-resident; h staged 32KB LDS. Col-split (7x less
//          per-CU U traffic than row-split) with FENCE-FREE exchange:
//          h stores sc0+sc1 (write-through to L3), h loads sc0+sc1 (bypass
//          L2 -> never stale -> NO acquire fence -> no L2 invalidate; r9's
//          304MB FETCH blowup was per-step L2 invalidation), relaxed
//          agent-scope atomic counters, explicit vmcnt(0) store->publish.
//          (r12 fix: removed unsupported tied uint4 "+v" asm touch -- the
//          vmcnt(0) with "memory" clobber already orders load->LDS-store.)

#define B_ 2048
#define T_ 50
#define F_ 256
#define H_ 256
#define NZ 1024      // 4H

typedef __attribute__((ext_vector_type(8))) short short8;
typedef __attribute__((ext_vector_type(4))) float f32x4;
typedef unsigned short ushort_t;
typedef unsigned int uint_t;

__device__ __forceinline__ ushort_t f2bf(float f) {
    uint_t u = __float_as_uint(f);
    return (ushort_t)((u + 0x7FFFu + ((u >> 16) & 1u)) >> 16);
}
__device__ __forceinline__ uint_t pack2bf(float lo, float hi) {
    return (uint_t)f2bf(lo) | ((uint_t)f2bf(hi) << 16);
}
__device__ __forceinline__ float bf2f(ushort_t u) {
    return __uint_as_float(((uint_t)u) << 16);
}
__device__ __forceinline__ float sigm(float z) {
    return __builtin_amdgcn_rcpf(1.0f + __builtin_amdgcn_exp2f(z * -1.44269504f));
}
__device__ __forceinline__ float tanh_f(float z) {
    return 2.0f * __builtin_amdgcn_rcpf(1.0f + __builtin_amdgcn_exp2f(z * -2.88539008f)) - 1.0f;
}
__device__ __forceinline__ float xz_at(uint2 u, int j) {
    uint_t v = (j < 2) ? u.x : u.y;
    v = (j & 1) ? (v >> 16) : (v & 0xFFFFu);
    return bf2f((ushort_t)v);
}

// -------- pack: fp32 [256][1024] -> bf16 frag-order panels ----------------
__global__ void pack_wu(const float* __restrict__ Wm, const float* __restrict__ Um,
                        ushort_t* __restrict__ W2, ushort_t* __restrict__ U2) {
    int gid  = blockIdx.x * 256 + threadIdx.x;   // 65536 total
    int lane = gid & 63;
    int nf   = (gid >> 6) & 7;
    int w    = (gid >> 9) & 7;
    int kf   = (gid >> 12) & 7;
    int mat  = gid >> 15;
    const float* src = mat ? Um : Wm;
    ushort_t* dst    = mat ? U2 : W2;
    int col = (nf >> 1) * 256 + w * 32 + (nf & 1) * 16 + (lane & 15);
    int kb  = kf * 32 + (lane >> 4) * 8;
    short8 v;
#pragma unroll
    for (int e = 0; e < 8; ++e)
        v[e] = (short)f2bf(src[(size_t)(kb + e) * NZ + col]);
    *(short8*)(dst + ((((size_t)kf * 8 + w) * 8 + nf) * 64 + lane) * 8) = v;
}

// -------- phase 1: xz[t] = x[:,t,:] @ W + b  (bf16, frag layout) ----------
__global__ __launch_bounds__(512, 2) void xw_gemm(
    const float* __restrict__ x, const float* __restrict__ bias,
    const ushort_t* __restrict__ W2, ushort_t* __restrict__ xz2) {
    __shared__ __align__(16) ushort_t As[32 * 256];   // 16 KB, swizzled

    const int tid = threadIdx.x;
    const int t = blockIdx.x, rb = blockIdx.y, row0 = rb * 32;
    const int w = tid >> 6, lane = tid & 63, r16 = lane & 15, q = lane >> 4;

    {
        int sr = tid >> 4, sc = tid & 15;
        const float* xp = x + ((size_t)(row0 + sr) * T_ + t) * F_ + sc * 16;
        float4 f0 = *(const float4*)(xp + 0);
        float4 f1 = *(const float4*)(xp + 4);
        float4 f2 = *(const float4*)(xp + 8);
        float4 f3 = *(const float4*)(xp + 12);
        uint4 u0 = {pack2bf(f0.x, f0.y), pack2bf(f0.z, f0.w),
                    pack2bf(f1.x, f1.y), pack2bf(f1.z, f1.w)};
        uint4 u1 = {pack2bf(f2.x, f2.y), pack2bf(f2.z, f2.w),
                    pack2bf(f3.x, f3.y), pack2bf(f3.z, f3.w)};
        int c0 = (2 * sc) ^ (sr & 7), c1 = (2 * sc + 1) ^ (sr & 7);
        *(uint4*)&As[sr * 256 + c0 * 8] = u0;
        *(uint4*)&As[sr * 256 + c1 * 8] = u1;
    }
    float bcol[8];
#pragma unroll
    for (int nf = 0; nf < 8; ++nf)
        bcol[nf] = bias[(nf >> 1) * 256 + w * 32 + (nf & 1) * 16 + r16];
    __syncthreads();

    f32x4 acc0[8], acc1[8];
#pragma unroll
    for (int nf = 0; nf < 8; ++nf) {
        acc0[nf] = (f32x4){0.f, 0.f, 0.f, 0.f};
        acc1[nf] = (f32x4){0.f, 0.f, 0.f, 0.f};
    }
    short8 SB0[8], SB1[8];

#define LOADB(BUF, KF_)                                                       \
    _Pragma("unroll") for (int nf = 0; nf < 8; ++nf)                          \
        BUF[nf] = *(const short8*)(W2 +                                       \
            ((((size_t)(KF_) * 8 + w) * 8 + nf) * 64 + lane) * 8);

#define MF1(BUF, KF_)                                                         \
    do {                                                                      \
        short8 a0_ = *(const short8*)&As[r16 * 256 + (((KF_)*4 + q) ^ (r16 & 7)) * 8];       \
        short8 a1_ = *(const short8*)&As[(16 + r16) * 256 + (((KF_)*4 + q) ^ (r16 & 7)) * 8];\
        _Pragma("unroll") for (int nf = 0; nf < 8; ++nf) {                    \
            acc0[nf] = __builtin_amdgcn_mfma_f32_16x16x32_bf16(a0_, BUF[nf], acc0[nf], 0, 0, 0); \
            acc1[nf] = __builtin_amdgcn_mfma_f32_16x16x32_bf16(a1_, BUF[nf], acc1[nf], 0, 0, 0); \
        }                                                                     \
    } while (0)

    LOADB(SB0, 0); LOADB(SB1, 1);
    MF1(SB0, 0); LOADB(SB0, 2);
    MF1(SB1, 1); LOADB(SB1, 3);
    MF1(SB0, 2); LOADB(SB0, 4);
    MF1(SB1, 3); LOADB(SB1, 5);
    MF1(SB0, 4); LOADB(SB0, 6);
    MF1(SB1, 5); LOADB(SB1, 7);
    MF1(SB0, 6);
    MF1(SB1, 7);

    uint2* outp = (uint2*)xz2;
    const size_t cb = (((size_t)t * 64 + rb) * 8 + w) * 16;
#pragma unroll
    for (int m = 0; m < 2; ++m) {
#pragma unroll
        for (int nf = 0; nf < 8; ++nf) {
            f32x4 a = m ? acc1[nf] : acc0[nf];
            float b = bcol[nf];
            uint2 o = {pack2bf(a[0] + b, a[1] + b), pack2bf(a[2] + b, a[3] + b)};
            outp[(cb + m * 8 + nf) * 64 + lane] = o;
        }
    }
#undef LOADB
#undef MF1
}

// -------- phase 2: col-split, fence-free L3 exchange ----------------------
__global__ __launch_bounds__(512, 1) void lstm_rec(
    const ushort_t* __restrict__ U2, const ushort_t* __restrict__ xz2,
    ushort_t* __restrict__ hg,   // [2][32][16384] swizzled bf16 h ping-pong
    int* __restrict__ cnt,       // [50][32] publish counters (memset 0/launch)
    float* __restrict__ outp, int T)
{
    __shared__ __align__(16) ushort_t UL[8 * 8 * 512];   // U-slice, 64 KB
    __shared__ __align__(16) ushort_t hL[64 * 256];      // h staged, 32 KB

    const int tid = threadIdx.x;
    const int rg = blockIdx.x >> 3, cg = blockIdx.x & 7;
    const int w = tid >> 6, lane = tid & 63, r16 = lane & 15, q = lane >> 4;
    const int m = w >> 1, hf = w & 1;

    // ---- one-time: U-slice -> LDS (8 slabs of 8 KB, linear) ----
#pragma unroll
    for (int kf = 0; kf < 8; ++kf) {
        const char* src = (const char*)(U2 + ((size_t)(kf * 8 + cg)) * 4096);
        __builtin_amdgcn_global_load_lds(
            (const __attribute__((address_space(1))) void*)(src + tid * 16),
            (__attribute__((address_space(3))) void*)((char*)UL + kf * 8192 + tid * 16),
            16, 0, 0);
    }
    // ---- h0 = 0 ----
#pragma unroll
    for (int k = 0; k < 4; ++k)
        *(uint4*)&hL[tid * 32 + k * 8] = (uint4){0, 0, 0, 0};

    const uint2* xzp = (const uint2*)xz2;
    const size_t xz_base = ((((size_t)(rg * 2 + (m >> 1))) * 8 + cg) * 16
                            + (size_t)(m & 1) * 8 + hf) * 64 + lane;
    const size_t XZ_T = (size_t)64 * 8 * 16 * 64;   // per-t stride in uint2

    f32x4 acc[4];
    f32x4 creg = (f32x4){0.f, 0.f, 0.f, 0.f};
    const int hcol = cg * 32 + hf * 16 + r16;       // this thread's h column

    __syncthreads();   // UL + hL ready (drains glds too)

#pragma clang loop unroll(disable)
    for (int t = 0; t < T; ++t) {
        // xz(t): independent of h -- issue before the spin, lands under it
        uint2 XZ[4];
#pragma unroll
        for (int g = 0; g < 4; ++g)
            XZ[g] = xzp[(size_t)t * XZ_T + xz_base + (size_t)g * 128];

        if (t > 0) {
            // wait for all 8 col-blocks of this row-group to publish h(t).
            // RELAXED agent atomic load -- no acquire fence, no L2 invalidate.
            if (tid == 0) {
                while (__hip_atomic_load(&cnt[t * 32 + rg], __ATOMIC_RELAXED,
                                         __HIP_MEMORY_SCOPE_AGENT) < 8)
                    __builtin_amdgcn_s_sleep(1);
            }
            __syncthreads();

            // restage h(t) from L3: sc0 sc1 loads BYPASS L2 -> never stale.
            uint4 hv0, hv1, hv2, hv3;
            {
                const char* hsrc = (const char*)(hg
                    + ((size_t)(t & 1) * 32 + rg) * 16384) + (size_t)tid * 64;
                asm volatile("global_load_dwordx4 %0, %1, off sc0 sc1"
                             : "=v"(hv0) : "v"(hsrc) : "memory");
                asm volatile("global_load_dwordx4 %0, %1, off sc0 sc1"
                             : "=v"(hv1) : "v"(hsrc + 16) : "memory");
                asm volatile("global_load_dwordx4 %0, %1, off sc0 sc1"
                             : "=v"(hv2) : "v"(hsrc + 32) : "memory");
                asm volatile("global_load_dwordx4 %0, %1, off sc0 sc1"
                             : "=v"(hv3) : "v"(hsrc + 48) : "memory");
                asm volatile("s_waitcnt vmcnt(0)" ::: "memory");
            }
            *(uint4*)&hL[tid * 32 + 0]  = hv0;
            *(uint4*)&hL[tid * 32 + 8]  = hv1;
            *(uint4*)&hL[tid * 32 + 16] = hv2;
            *(uint4*)&hL[tid * 32 + 24] = hv3;
            __syncthreads();   // hL ready for all waves
        }

        // ---- MFMA: 16 rows x (4 gates x 16 cols) per wave ----
#pragma unroll
        for (int g = 0; g < 4; ++g) acc[g] = (f32x4){0.f, 0.f, 0.f, 0.f};

        __builtin_amdgcn_s_setprio(1);
#pragma unroll
        for (int kf = 0; kf < 8; ++kf) {
            short8 a = *(const short8*)&hL[(m * 16 + r16) * 256
                                           + ((kf * 4 + q) ^ (r16 & 7)) * 8];
#pragma unroll
            for (int g = 0; g < 4; ++g) {
                short8 b = *(const short8*)&UL[((kf * 8 + g * 2 + hf)) * 512 + lane * 8];
                acc[g] = __builtin_amdgcn_mfma_f32_16x16x32_bf16(a, b, acc[g], 0, 0, 0);
            }
        }
        __builtin_amdgcn_s_setprio(0);

        // ---- epilogue: gates + cell update for 4 rows x 1 col ----
        ushort_t* hdst = hg + ((size_t)((t + 1) & 1) * 32 + rg) * 16384;
#pragma unroll
        for (int j = 0; j < 4; ++j) {
            float zi = acc[0][j] + xz_at(XZ[0], j);
            float zf = acc[1][j] + xz_at(XZ[1], j);
            float zg = acc[2][j] + xz_at(XZ[2], j);
            float zo = acc[3][j] + xz_at(XZ[3], j);
            float ig = sigm(zi);
            float fg = sigm(zf);
            float gg = tanh_f(zg);
            float og = sigm(zo);
            float cn = fg * creg[j] + ig * gg;
            float hv = og * tanh_f(cn);
            creg[j] = cn;
            int row = m * 16 + q * 4 + j;                    // 0..63
            if (t == T_ - 1) {
                size_t oi = (size_t)(rg * 64 + row) * H_ + hcol;
                outp[oi] = hv;
                outp[(size_t)B_ * H_ + oi] = cn;
            } else {
                // sc0 sc1 store: write-through to L3 (device-visible, no fence)
                ushort_t* p = hdst + row * 256
                              + (((hcol >> 3) ^ (row & 7)) * 8) + (hcol & 7);
                uint_t v = (uint_t)f2bf(hv);
                asm volatile("global_store_short %0, %1, off sc0 sc1"
                             :: "v"(p), "v"(v) : "memory");
            }
        }

        if (t < T_ - 1) {
            // order: h stores retired (at L3) -> then publish
            asm volatile("s_waitcnt vmcnt(0)" ::: "memory");
            __syncthreads();   // all waves' stores retired
            if (tid == 0)
                __hip_atomic_fetch_add(&cnt[(t + 1) * 32 + rg], 1,
                                       __ATOMIC_RELAXED, __HIP_MEMORY_SCOPE_AGENT);
        }
    }
}

extern "C" void kernel_launch(void* const* d_in, const int* in_sizes, int n_in,
                              void* d_out, int out_size, void* d_ws, size_t ws_size,
                              hipStream_t stream) {
    const float* x    = (const float*)d_in[0];
    const float* Wm   = (const float*)d_in[1];
    const float* Um   = (const float*)d_in[2];
    const float* bias = (const float*)d_in[3];

    // ws (ushort units): W2 512KB | U2 512KB | xz2 210MB | hg 2MB | cnt 6.4KB
    ushort_t* W2  = (ushort_t*)d_ws;
    ushort_t* U2  = W2 + 262144;
    ushort_t* xz2 = U2 + 262144;
    ushort_t* hg  = xz2 + (size_t)T_ * 2048 * 1024;
    int*      cnt = (int*)(hg + (size_t)2 * 32 * 16384);

    (void)hipMemsetAsync(cnt, 0, (size_t)T_ * 32 * sizeof(int), stream);
    pack_wu<<<256, 256, 0, stream>>>(Wm, Um, W2, U2);
    dim3 g1(T_, 64);
    xw_gemm<<<g1, 512, 0, stream>>>(x, bias, W2, xz2);
    lstm_rec<<<256, 512, 0, stream>>>(U2, xz2, hg, cnt, (float*)d_out, T_);
}

// Round 14
// 303.968 us; speedup vs baseline: 6.9888x; 1.9385x over previous
//
#include <hip/hip_runtime.h>

// LSTM recurrence, 50 steps. B=2048, T=50, F=256, H=256, gates i,f,g,o.
// Phase 0: pack W (bf16 frag order) + quantize U to int8 with per-column
//          scales (accuracy ~ bf16: rel err 2^-8 with column max scaling).
// Phase 1: xz = x@W + b for ALL timesteps (parallel GEMM), bf16 frag layout.
// Phase 2: ONE persistent kernel, 128 blocks x 16 batch rows, row-split only
//          (r9/r13: cross-block exchange = L2/L3 disaster, abandoned).
//          U i8 = 256 KB: kf0-1 (128 KB) LDS-resident, kf2-3 (128 KB/step)
//          streamed from L2 -- 1/3 of r7's bf16 stream, and stream values
//          are SINGLE-USE so the RA has nothing to rematerialize (the r5-r10
//          failure needed reused panels). i8 MFMA 16x16x64 = 2x bf16 rate.
//          h kept as i8 in LDS (|h|<1 structurally, fixed x127 scale);
//          dequant z = acc_i32 * (colmax/127^2). c stays fp32 in registers.
//          Streams issued first, XZ(t) last (in-order vmcnt: L2 waits never
//          see HBM latency); XZ consumed in epilogue under MFMA cover.

#define B_ 2048
#define T_ 50
#define F_ 256
#define H_ 256
#define NZ 1024      // 4H

typedef __attribute__((ext_vector_type(8))) short short8;
typedef __attribute__((ext_vector_type(4))) float f32x4;
typedef __attribute__((ext_vector_type(4))) int i32x4;
typedef unsigned short ushort_t;
typedef unsigned int uint_t;

__device__ __forceinline__ ushort_t f2bf(float f) {
    uint_t u = __float_as_uint(f);
    return (ushort_t)((u + 0x7FFFu + ((u >> 16) & 1u)) >> 16);
}
__device__ __forceinline__ uint_t pack2bf(float lo, float hi) {
    return (uint_t)f2bf(lo) | ((uint_t)f2bf(hi) << 16);
}
__device__ __forceinline__ float bf2f(ushort_t u) {
    return __uint_as_float(((uint_t)u) << 16);
}
__device__ __forceinline__ float sigm(float z) {
    return __builtin_amdgcn_rcpf(1.0f + __builtin_amdgcn_exp2f(z * -1.44269504f));
}
__device__ __forceinline__ float tanh_f(float z) {
    return 2.0f * __builtin_amdgcn_rcpf(1.0f + __builtin_amdgcn_exp2f(z * -2.88539008f)) - 1.0f;
}
__device__ __forceinline__ float xz_at(uint2 u, int j) {
    uint_t v = (j < 2) ? u.x : u.y;
    v = (j & 1) ? (v >> 16) : (v & 0xFFFFu);
    return bf2f((ushort_t)v);
}

// -------- pack W: fp32 [256][1024] -> bf16 frag-order panels ---------------
__global__ void pack_w(const float* __restrict__ Wm, ushort_t* __restrict__ W2) {
    int gid  = blockIdx.x * 256 + threadIdx.x;   // 32768 total
    int lane = gid & 63;
    int nf   = (gid >> 6) & 7;
    int w    = (gid >> 9) & 7;
    int kf   = (gid >> 12) & 7;
    int col = (nf >> 1) * 256 + w * 32 + (nf & 1) * 16 + (lane & 15);
    int kb  = kf * 32 + (lane >> 4) * 8;
    short8 v;
#pragma unroll
    for (int e = 0; e < 8; ++e)
        v[e] = (short)f2bf(Wm[(size_t)(kb + e) * NZ + col]);
    *(short8*)(W2 + ((((size_t)kf * 8 + w) * 8 + nf) * 64 + lane) * 8) = v;
}

// -------- U scales: per-column max -> quant scale + dequant factor --------
__global__ void pack_scale(const float* __restrict__ Um,
                           float* __restrict__ scq, float* __restrict__ scd) {
    int j = blockIdx.x * 256 + threadIdx.x;   // 1024 threads
    float mx = 0.f;
    for (int i = 0; i < H_; ++i) mx = fmaxf(mx, fabsf(Um[(size_t)i * NZ + j]));
    scq[j] = (mx > 0.f) ? (127.0f / mx) : 0.f;
    scd[j] = mx * (1.0f / 16129.0f);          // mx/127^2
}

// -------- pack U: fp32 -> i8 frag order for mfma_i32_16x16x64_i8 ----------
// dst byte: ((kf*8 + w)*8 + nf)*1024 + lane*16 + e
// value    = round(U[kf*64 + (lane>>4)*16 + e][col(nf,w,lane&15)] * scq[col])
__global__ void pack_u8(const float* __restrict__ Um,
                        const float* __restrict__ scq, char* __restrict__ U8) {
    int gid  = blockIdx.x * 256 + threadIdx.x;   // 16384 total
    int lane = gid & 63;
    int nf   = (gid >> 6) & 7;
    int w    = (gid >> 9) & 7;
    int kf   = (gid >> 12) & 3;
    int col = (nf >> 1) * 256 + w * 32 + (nf & 1) * 16 + (lane & 15);
    int k0  = kf * 64 + (lane >> 4) * 16;
    float qs = scq[col];
    union { char c[16]; int4 v; } u;
#pragma unroll
    for (int e = 0; e < 16; ++e)
        u.c[e] = (char)__float2int_rn(Um[(size_t)(k0 + e) * NZ + col] * qs);
    *(int4*)(U8 + (((size_t)(kf * 8 + w) * 8 + nf) << 10) + (size_t)lane * 16) = u.v;
}

// -------- phase 1: xz[t] = x[:,t,:] @ W + b  (bf16, frag layout) ----------
__global__ __launch_bounds__(512, 2) void xw_gemm(
    const float* __restrict__ x, const float* __restrict__ bias,
    const ushort_t* __restrict__ W2, ushort_t* __restrict__ xz2) {
    __shared__ __align__(16) ushort_t As[32 * 256];   // 16 KB, swizzled

    const int tid = threadIdx.x;
    const int t = blockIdx.x, rb = blockIdx.y, row0 = rb * 32;
    const int w = tid >> 6, lane = tid & 63, r16 = lane & 15, q = lane >> 4;

    {
        int sr = tid >> 4, sc = tid & 15;
        const float* xp = x + ((size_t)(row0 + sr) * T_ + t) * F_ + sc * 16;
        float4 f0 = *(const float4*)(xp + 0);
        float4 f1 = *(const float4*)(xp + 4);
        float4 f2 = *(const float4*)(xp + 8);
        float4 f3 = *(const float4*)(xp + 12);
        uint4 u0 = {pack2bf(f0.x, f0.y), pack2bf(f0.z, f0.w),
                    pack2bf(f1.x, f1.y), pack2bf(f1.z, f1.w)};
        uint4 u1 = {pack2bf(f2.x, f2.y), pack2bf(f2.z, f2.w),
                    pack2bf(f3.x, f3.y), pack2bf(f3.z, f3.w)};
        int c0 = (2 * sc) ^ (sr & 7), c1 = (2 * sc + 1) ^ (sr & 7);
        *(uint4*)&As[sr * 256 + c0 * 8] = u0;
        *(uint4*)&As[sr * 256 + c1 * 8] = u1;
    }
    float bcol[8];
#pragma unroll
    for (int nf = 0; nf < 8; ++nf)
        bcol[nf] = bias[(nf >> 1) * 256 + w * 32 + (nf & 1) * 16 + r16];
    __syncthreads();

    f32x4 acc0[8], acc1[8];
#pragma unroll
    for (int nf = 0; nf < 8; ++nf) {
        acc0[nf] = (f32x4){0.f, 0.f, 0.f, 0.f};
        acc1[nf] = (f32x4){0.f, 0.f, 0.f, 0.f};
    }
    short8 SB0[8], SB1[8];

#define LOADB(BUF, KF_)                                                       \
    _Pragma("unroll") for (int nf = 0; nf < 8; ++nf)                          \
        BUF[nf] = *(const short8*)(W2 +                                       \
            ((((size_t)(KF_) * 8 + w) * 8 + nf) * 64 + lane) * 8);

#define MF1(BUF, KF_)                                                         \
    do {                                                                      \
        short8 a0_ = *(const short8*)&As[r16 * 256 + (((KF_)*4 + q) ^ (r16 & 7)) * 8];       \
        short8 a1_ = *(const short8*)&As[(16 + r16) * 256 + (((KF_)*4 + q) ^ (r16 & 7)) * 8];\
        _Pragma("unroll") for (int nf = 0; nf < 8; ++nf) {                    \
            acc0[nf] = __builtin_amdgcn_mfma_f32_16x16x32_bf16(a0_, BUF[nf], acc0[nf], 0, 0, 0); \
            acc1[nf] = __builtin_amdgcn_mfma_f32_16x16x32_bf16(a1_, BUF[nf], acc1[nf], 0, 0, 0); \
        }                                                                     \
    } while (0)

    LOADB(SB0, 0); LOADB(SB1, 1);
    MF1(SB0, 0); LOADB(SB0, 2);
    MF1(SB1, 1); LOADB(SB1, 3);
    MF1(SB0, 2); LOADB(SB0, 4);
    MF1(SB1, 3); LOADB(SB1, 5);
    MF1(SB0, 4); LOADB(SB0, 6);
    MF1(SB1, 5); LOADB(SB1, 7);
    MF1(SB0, 6);
    MF1(SB1, 7);

    uint2* outp = (uint2*)xz2;
    const size_t cb = (((size_t)t * 64 + rb) * 8 + w) * 16;
#pragma unroll
    for (int m = 0; m < 2; ++m) {
#pragma unroll
        for (int nf = 0; nf < 8; ++nf) {
            f32x4 a = m ? acc1[nf] : acc0[nf];
            float b = bcol[nf];
            uint2 o = {pack2bf(a[0] + b, a[1] + b), pack2bf(a[2] + b, a[3] + b)};
            outp[(cb + m * 8 + nf) * 64 + lane] = o;
        }
    }
#undef LOADB
#undef MF1
}

// -------- phase 2: persistent recurrence, i8 U, 128 blocks x 16 rows ------
__global__ __launch_bounds__(512, 1) void lstm_rec(
    const char* __restrict__ U8, const float* __restrict__ scd,
    const ushort_t* __restrict__ xz2, float* __restrict__ outp, int T) {
    __shared__ __align__(16) char UL[131072];     // U kf0,kf1 i8 (128 KB)
    __shared__ __align__(16) char hbc[2][4096];   // h i8 dbuf (2 x 4 KB)

    const int tid = threadIdx.x;
    const int rb = blockIdx.x, row0 = rb * 16;
    const int w = tid >> 6, lane = tid & 63, r16 = lane & 15, q = lane >> 4;

    // one-time: kf0-1 -> LDS (linear 128 KB)
#pragma unroll
    for (int i = 0; i < 16; ++i) {
        int off = i * 8192 + tid * 16;
        __builtin_amdgcn_global_load_lds(
            (const __attribute__((address_space(1))) void*)(U8 + off),
            (__attribute__((address_space(3))) void*)(UL + off),
            16, 0, 0);
    }
    // h0 = 0
    *(uint2*)&hbc[0][tid * 8] = (uint2){0, 0};

    // dequant factors for this thread's 8 z-cols (gate g, half hf: nf=2g+hf)
    float d[8];
#pragma unroll
    for (int nf = 0; nf < 8; ++nf)
        d[nf] = scd[(nf >> 1) * 256 + w * 32 + (nf & 1) * 16 + r16];

    const uint2* xzp = (const uint2*)xz2;
    const size_t cbconst = (((size_t)(rb >> 1)) * 8 + w) * 16 + (size_t)(rb & 1) * 8;
    const uint2* xzb = xzp + cbconst * 64 + lane;
    const size_t TSTRIDE = (size_t)8192 * 64;   // per-t stride in uint2

    // A-frag from i8 h LDS: row=r16, 16B k-chunk (kf*4+q), XOR-swizzled
#define AFRAG8(HP_, KF_)                                                      \
    (*(const i32x4*)&(HP_)[r16 * 256 + ((((KF_)*4 + q) ^ (r16 & 7)) << 4)])

    i32x4 acc[8];
    f32x4 creg[2];
    creg[0] = (f32x4){0.f, 0.f, 0.f, 0.f};
    creg[1] = (f32x4){0.f, 0.f, 0.f, 0.f};

    int cur = 0;
    __syncthreads();   // UL + hbc[0] ready (drains glds)

#pragma clang loop unroll(disable)
    for (int t = 0; t < T; ++t) {
        const char* hc = hbc[cur];
        char* hn = hbc[cur ^ 1];

        // stream kf2,kf3 FIRST (L2, oldest in vmcnt queue)
        i32x4 S2[8], S3[8];
#pragma unroll
        for (int nf = 0; nf < 8; ++nf)
            S2[nf] = *(const i32x4*)(U8 + (((size_t)(2 * 8 + w) * 8 + nf) << 10)
                                     + (size_t)lane * 16);
#pragma unroll
        for (int nf = 0; nf < 8; ++nf)
            S3[nf] = *(const i32x4*)(U8 + (((size_t)(3 * 8 + w) * 8 + nf) << 10)
                                     + (size_t)lane * 16);
        // XZ(t) LAST (L3/HBM; consumed in epilogue under full MFMA cover)
        uint2 XZ[8];
#pragma unroll
        for (int k = 0; k < 8; ++k) XZ[k] = xzb[(size_t)t * TSTRIDE + (size_t)k * 64];

#pragma unroll
        for (int nf = 0; nf < 8; ++nf) acc[nf] = (i32x4){0, 0, 0, 0};

        __builtin_amdgcn_s_setprio(1);
        // kf0,kf1 from LDS (no vmem dependency)
#pragma unroll
        for (int kf = 0; kf < 2; ++kf) {
            i32x4 a = AFRAG8(hc, kf);
#pragma unroll
            for (int nf = 0; nf < 8; ++nf) {
                i32x4 b = *(const i32x4*)&UL[(((size_t)(kf * 8 + w) * 8 + nf) << 10)
                                             + (size_t)lane * 16];
                acc[nf] = __builtin_amdgcn_mfma_i32_16x16x64_i8(a, b, acc[nf], 0, 0, 0);
            }
        }
        // kf2, kf3 from stream regs
        {
            i32x4 a2 = AFRAG8(hc, 2);
#pragma unroll
            for (int nf = 0; nf < 8; ++nf)
                acc[nf] = __builtin_amdgcn_mfma_i32_16x16x64_i8(a2, S2[nf], acc[nf], 0, 0, 0);
            i32x4 a3 = AFRAG8(hc, 3);
#pragma unroll
            for (int nf = 0; nf < 8; ++nf)
                acc[nf] = __builtin_amdgcn_mfma_i32_16x16x64_i8(a3, S3[nf], acc[nf], 0, 0, 0);
        }
        __builtin_amdgcn_s_setprio(0);

        // epilogue: dequant + xz, gates, cell update, h -> other buffer (i8)
#pragma unroll
        for (int hf = 0; hf < 2; ++hf) {
#pragma unroll
            for (int j = 0; j < 4; ++j) {
                float zi = (float)acc[0 + hf][j] * d[0 + hf] + xz_at(XZ[0 + hf], j);
                float zf = (float)acc[2 + hf][j] * d[2 + hf] + xz_at(XZ[2 + hf], j);
                float zg = (float)acc[4 + hf][j] * d[4 + hf] + xz_at(XZ[4 + hf], j);
                float zo = (float)acc[6 + hf][j] * d[6 + hf] + xz_at(XZ[6 + hf], j);
                float ig = sigm(zi);
                float fg = sigm(zf);
                float gg = tanh_f(zg);
                float og = sigm(zo);
                float cn = fg * creg[hf][j] + ig * gg;
                float hv = og * tanh_f(cn);
                creg[hf][j] = cn;
                int row = q * 4 + j;
                int ch  = w * 32 + hf * 16 + r16;
                if (t == T_ - 1) {
                    size_t oi = (size_t)(row0 + row) * H_ + ch;
                    outp[oi] = hv;
                    outp[(size_t)B_ * H_ + oi] = cn;
                } else {
                    hn[row * 256 + (((ch >> 4) ^ (row & 7)) << 4) + (ch & 15)] =
                        (char)__float2int_rn(hv * 127.0f);
                }
            }
        }

        // raw barrier: drain LDS writes only
        asm volatile("s_waitcnt lgkmcnt(0)" ::: "memory");
        __builtin_amdgcn_s_barrier();
        cur ^= 1;
    }
#undef AFRAG8
}

extern "C" void kernel_launch(void* const* d_in, const int* in_sizes, int n_in,
                              void* d_out, int out_size, void* d_ws, size_t ws_size,
                              hipStream_t stream) {
    const float* x    = (const float*)d_in[0];
    const float* Wm   = (const float*)d_in[1];
    const float* Um   = (const float*)d_in[2];
    const float* bias = (const float*)d_in[3];

    // ws bytes: W2 @0 (512K) | U8 @512K (256K) | scq @768K (4K) |
    //           scd @772K (4K) | xz2 @776K (210 MB)      (ws = 400 MiB)
    ushort_t* W2  = (ushort_t*)d_ws;
    char*     U8  = (char*)d_ws + 524288;
    float*    scq = (float*)((char*)d_ws + 786432);
    float*    scd = (float*)((char*)d_ws + 790528);
    ushort_t* xz2 = (ushort_t*)((char*)d_ws + 794624);

    pack_w<<<128, 256, 0, stream>>>(Wm, W2);
    pack_scale<<<4, 256, 0, stream>>>(Um, scq, scd);
    pack_u8<<<64, 256, 0, stream>>>(Um, scq, U8);
    dim3 g1(T_, 64);
    xw_gemm<<<g1, 512, 0, stream>>>(x, bias, W2, xz2);
    lstm_rec<<<128, 512, 0, stream>>>(U8, scd, xz2, (float*)d_out, T_);
}

// Round 15
// 279.983 us; speedup vs baseline: 7.5875x; 1.0857x over previous
//
#include <hip/hip_runtime.h>

// LSTM recurrence, 50 steps. B=2048, T=50, F=256, H=256, gates i,f,g,o.
// Phase 0: pack W (bf16 frag order) + quantize U to int8 (per-column scale).
// Phase 1: xz = x@W + b, BM=64 tile (r15: doubles MFMA:B-load ratio to 4:1,
//          halves W2 L2 re-reads vs r14's BM=32 which sat at 16% MfmaUtil).
// Phase 2: persistent recurrence, 128 blocks x 16 rows (UNCHANGED from r14:
//          i8 U, kf0-1 LDS-resident, kf2-3 streamed single-use, i8 h dbuf,
//          one lgkm-only barrier/step). r14 = 304us, absmax 0.0117.

#define B_ 2048
#define T_ 50
#define F_ 256
#define H_ 256
#define NZ 1024      // 4H

typedef __attribute__((ext_vector_type(8))) short short8;
typedef __attribute__((ext_vector_type(4))) float f32x4;
typedef __attribute__((ext_vector_type(4))) int i32x4;
typedef unsigned short ushort_t;
typedef unsigned int uint_t;

__device__ __forceinline__ ushort_t f2bf(float f) {
    uint_t u = __float_as_uint(f);
    return (ushort_t)((u + 0x7FFFu + ((u >> 16) & 1u)) >> 16);
}
__device__ __forceinline__ uint_t pack2bf(float lo, float hi) {
    return (uint_t)f2bf(lo) | ((uint_t)f2bf(hi) << 16);
}
__device__ __forceinline__ float bf2f(ushort_t u) {
    return __uint_as_float(((uint_t)u) << 16);
}
__device__ __forceinline__ float sigm(float z) {
    return __builtin_amdgcn_rcpf(1.0f + __builtin_amdgcn_exp2f(z * -1.44269504f));
}
__device__ __forceinline__ float tanh_f(float z) {
    return 2.0f * __builtin_amdgcn_rcpf(1.0f + __builtin_amdgcn_exp2f(z * -2.88539008f)) - 1.0f;
}
__device__ __forceinline__ float xz_at(uint2 u, int j) {
    uint_t v = (j < 2) ? u.x : u.y;
    v = (j & 1) ? (v >> 16) : (v & 0xFFFFu);
    return bf2f((ushort_t)v);
}

// -------- pack W: fp32 [256][1024] -> bf16 frag-order panels ---------------
__global__ void pack_w(const float* __restrict__ Wm, ushort_t* __restrict__ W2) {
    int gid  = blockIdx.x * 256 + threadIdx.x;   // 32768 total
    int lane = gid & 63;
    int nf   = (gid >> 6) & 7;
    int w    = (gid >> 9) & 7;
    int kf   = (gid >> 12) & 7;
    int col = (nf >> 1) * 256 + w * 32 + (nf & 1) * 16 + (lane & 15);
    int kb  = kf * 32 + (lane >> 4) * 8;
    short8 v;
#pragma unroll
    for (int e = 0; e < 8; ++e)
        v[e] = (short)f2bf(Wm[(size_t)(kb + e) * NZ + col]);
    *(short8*)(W2 + ((((size_t)kf * 8 + w) * 8 + nf) * 64 + lane) * 8) = v;
}

// -------- U scales: per-column max -> quant scale + dequant factor --------
__global__ void pack_scale(const float* __restrict__ Um,
                           float* __restrict__ scq, float* __restrict__ scd) {
    int j = blockIdx.x * 256 + threadIdx.x;   // 1024 threads
    float mx = 0.f;
    for (int i = 0; i < H_; ++i) mx = fmaxf(mx, fabsf(Um[(size_t)i * NZ + j]));
    scq[j] = (mx > 0.f) ? (127.0f / mx) : 0.f;
    scd[j] = mx * (1.0f / 16129.0f);          // mx/127^2
}

// -------- pack U: fp32 -> i8 frag order for mfma_i32_16x16x64_i8 ----------
__global__ void pack_u8(const float* __restrict__ Um,
                        const float* __restrict__ scq, char* __restrict__ U8) {
    int gid  = blockIdx.x * 256 + threadIdx.x;   // 16384 total
    int lane = gid & 63;
    int nf   = (gid >> 6) & 7;
    int w    = (gid >> 9) & 7;
    int kf   = (gid >> 12) & 3;
    int col = (nf >> 1) * 256 + w * 32 + (nf & 1) * 16 + (lane & 15);
    int k0  = kf * 64 + (lane >> 4) * 16;
    float qs = scq[col];
    union { char c[16]; int4 v; } u;
#pragma unroll
    for (int e = 0; e < 16; ++e)
        u.c[e] = (char)__float2int_rn(Um[(size_t)(k0 + e) * NZ + col] * qs);
    *(int4*)(U8 + (((size_t)(kf * 8 + w) * 8 + nf) << 10) + (size_t)lane * 16) = u.v;
}

// -------- phase 1: xz[t] = x[:,t,:] @ W + b, BM=64 ------------------------
__global__ __launch_bounds__(512, 2) void xw_gemm(
    const float* __restrict__ x, const float* __restrict__ bias,
    const ushort_t* __restrict__ W2, ushort_t* __restrict__ xz2) {
    __shared__ __align__(16) ushort_t As[64 * 256];   // 32 KB, swizzled

    const int tid = threadIdx.x;
    const int t = blockIdx.x, rb = blockIdx.y, row0 = rb * 64;
    const int w = tid >> 6, lane = tid & 63, r16 = lane & 15, q = lane >> 4;

    // stage A: 64 rows x 256 k, fp32->bf16, chunk-XOR swizzle (2 passes)
    {
        int sr = tid >> 4, sc = tid & 15;
#pragma unroll
        for (int rr = 0; rr < 64; rr += 32) {
            const float* xp = x + ((size_t)(row0 + rr + sr) * T_ + t) * F_ + sc * 16;
            float4 f0 = *(const float4*)(xp + 0);
            float4 f1 = *(const float4*)(xp + 4);
            float4 f2 = *(const float4*)(xp + 8);
            float4 f3 = *(const float4*)(xp + 12);
            uint4 u0 = {pack2bf(f0.x, f0.y), pack2bf(f0.z, f0.w),
                        pack2bf(f1.x, f1.y), pack2bf(f1.z, f1.w)};
            uint4 u1 = {pack2bf(f2.x, f2.y), pack2bf(f2.z, f2.w),
                        pack2bf(f3.x, f3.y), pack2bf(f3.z, f3.w)};
            int c0 = (2 * sc) ^ (sr & 7), c1 = (2 * sc + 1) ^ (sr & 7);
            *(uint4*)&As[(rr + sr) * 256 + c0 * 8] = u0;
            *(uint4*)&As[(rr + sr) * 256 + c1 * 8] = u1;
        }
    }
    float bcol[8];
#pragma unroll
    for (int nf = 0; nf < 8; ++nf)
        bcol[nf] = bias[(nf >> 1) * 256 + w * 32 + (nf & 1) * 16 + r16];
    __syncthreads();

    f32x4 acc[4][8];
#pragma unroll
    for (int m = 0; m < 4; ++m)
#pragma unroll
        for (int nf = 0; nf < 8; ++nf) acc[m][nf] = (f32x4){0.f, 0.f, 0.f, 0.f};
    short8 SB0[8], SB1[8];

#define LOADB(BUF, KF_)                                                       \
    _Pragma("unroll") for (int nf = 0; nf < 8; ++nf)                          \
        BUF[nf] = *(const short8*)(W2 +                                       \
            ((((size_t)(KF_) * 8 + w) * 8 + nf) * 64 + lane) * 8);

#define MF1(BUF, KF_)                                                         \
    do {                                                                      \
        _Pragma("unroll") for (int m = 0; m < 4; ++m) {                       \
            short8 a_ = *(const short8*)&As[(m * 16 + r16) * 256              \
                                            + (((KF_)*4 + q) ^ (r16 & 7)) * 8];\
            _Pragma("unroll") for (int nf = 0; nf < 8; ++nf)                  \
                acc[m][nf] = __builtin_amdgcn_mfma_f32_16x16x32_bf16(         \
                    a_, BUF[nf], acc[m][nf], 0, 0, 0);                        \
        }                                                                     \
    } while (0)

    LOADB(SB0, 0); LOADB(SB1, 1);
    MF1(SB0, 0); LOADB(SB0, 2);
    MF1(SB1, 1); LOADB(SB1, 3);
    MF1(SB0, 2); LOADB(SB0, 4);
    MF1(SB1, 3); LOADB(SB1, 5);
    MF1(SB0, 4); LOADB(SB0, 6);
    MF1(SB1, 5); LOADB(SB1, 7);
    MF1(SB0, 6);
    MF1(SB1, 7);

    // epilogue: writer emits the SAME 32-row frag layout lstm_rec reads:
    // rb32 = rb*2 + (m>>1), half = m&1
    uint2* outp = (uint2*)xz2;
#pragma unroll
    for (int m = 0; m < 4; ++m) {
        const size_t cb = (((size_t)t * 64 + (size_t)(rb * 2 + (m >> 1))) * 8 + w) * 16
                        + (size_t)(m & 1) * 8;
#pragma unroll
        for (int nf = 0; nf < 8; ++nf) {
            f32x4 a = acc[m][nf];
            float b = bcol[nf];
            uint2 o = {pack2bf(a[0] + b, a[1] + b), pack2bf(a[2] + b, a[3] + b)};
            outp[(cb + nf) * 64 + lane] = o;
        }
    }
#undef LOADB
#undef MF1
}

// -------- phase 2: persistent recurrence, i8 U (UNCHANGED from r14) -------
__global__ __launch_bounds__(512, 1) void lstm_rec(
    const char* __restrict__ U8, const float* __restrict__ scd,
    const ushort_t* __restrict__ xz2, float* __restrict__ outp, int T) {
    __shared__ __align__(16) char UL[131072];     // U kf0,kf1 i8 (128 KB)
    __shared__ __align__(16) char hbc[2][4096];   // h i8 dbuf (2 x 4 KB)

    const int tid = threadIdx.x;
    const int rb = blockIdx.x, row0 = rb * 16;
    const int w = tid >> 6, lane = tid & 63, r16 = lane & 15, q = lane >> 4;

#pragma unroll
    for (int i = 0; i < 16; ++i) {
        int off = i * 8192 + tid * 16;
        __builtin_amdgcn_global_load_lds(
            (const __attribute__((address_space(1))) void*)(U8 + off),
            (__attribute__((address_space(3))) void*)(UL + off),
            16, 0, 0);
    }
    *(uint2*)&hbc[0][tid * 8] = (uint2){0, 0};

    float d[8];
#pragma unroll
    for (int nf = 0; nf < 8; ++nf)
        d[nf] = scd[(nf >> 1) * 256 + w * 32 + (nf & 1) * 16 + r16];

    const uint2* xzp = (const uint2*)xz2;
    const size_t cbconst = (((size_t)(rb >> 1)) * 8 + w) * 16 + (size_t)(rb & 1) * 8;
    const uint2* xzb = xzp + cbconst * 64 + lane;
    const size_t TSTRIDE = (size_t)8192 * 64;

#define AFRAG8(HP_, KF_)                                                      \
    (*(const i32x4*)&(HP_)[r16 * 256 + ((((KF_)*4 + q) ^ (r16 & 7)) << 4)])

    i32x4 acc[8];
    f32x4 creg[2];
    creg[0] = (f32x4){0.f, 0.f, 0.f, 0.f};
    creg[1] = (f32x4){0.f, 0.f, 0.f, 0.f};

    int cur = 0;
    __syncthreads();

#pragma clang loop unroll(disable)
    for (int t = 0; t < T; ++t) {
        const char* hc = hbc[cur];
        char* hn = hbc[cur ^ 1];

        i32x4 S2[8], S3[8];
#pragma unroll
        for (int nf = 0; nf < 8; ++nf)
            S2[nf] = *(const i32x4*)(U8 + (((size_t)(2 * 8 + w) * 8 + nf) << 10)
                                     + (size_t)lane * 16);
#pragma unroll
        for (int nf = 0; nf < 8; ++nf)
            S3[nf] = *(const i32x4*)(U8 + (((size_t)(3 * 8 + w) * 8 + nf) << 10)
                                     + (size_t)lane * 16);
        uint2 XZ[8];
#pragma unroll
        for (int k = 0; k < 8; ++k) XZ[k] = xzb[(size_t)t * TSTRIDE + (size_t)k * 64];

#pragma unroll
        for (int nf = 0; nf < 8; ++nf) acc[nf] = (i32x4){0, 0, 0, 0};

        __builtin_amdgcn_s_setprio(1);
#pragma unroll
        for (int kf = 0; kf < 2; ++kf) {
            i32x4 a = AFRAG8(hc, kf);
#pragma unroll
            for (int nf = 0; nf < 8; ++nf) {
                i32x4 b = *(const i32x4*)&UL[(((size_t)(kf * 8 + w) * 8 + nf) << 10)
                                             + (size_t)lane * 16];
                acc[nf] = __builtin_amdgcn_mfma_i32_16x16x64_i8(a, b, acc[nf], 0, 0, 0);
            }
        }
        {
            i32x4 a2 = AFRAG8(hc, 2);
#pragma unroll
            for (int nf = 0; nf < 8; ++nf)
                acc[nf] = __builtin_amdgcn_mfma_i32_16x16x64_i8(a2, S2[nf], acc[nf], 0, 0, 0);
            i32x4 a3 = AFRAG8(hc, 3);
#pragma unroll
            for (int nf = 0; nf < 8; ++nf)
                acc[nf] = __builtin_amdgcn_mfma_i32_16x16x64_i8(a3, S3[nf], acc[nf], 0, 0, 0);
        }
        __builtin_amdgcn_s_setprio(0);

#pragma unroll
        for (int hf = 0; hf < 2; ++hf) {
#pragma unroll
            for (int j = 0; j < 4; ++j) {
                float zi = (float)acc[0 + hf][j] * d[0 + hf] + xz_at(XZ[0 + hf], j);
                float zf = (float)acc[2 + hf][j] * d[2 + hf] + xz_at(XZ[2 + hf], j);
                float zg = (float)acc[4 + hf][j] * d[4 + hf] + xz_at(XZ[4 + hf], j);
                float zo = (float)acc[6 + hf][j] * d[6 + hf] + xz_at(XZ[6 + hf], j);
                float ig = sigm(zi);
                float fg = sigm(zf);
                float gg = tanh_f(zg);
                float og = sigm(zo);
                float cn = fg * creg[hf][j] + ig * gg;
                float hv = og * tanh_f(cn);
                creg[hf][j] = cn;
                int row = q * 4 + j;
                int ch  = w * 32 + hf * 16 + r16;
                if (t == T_ - 1) {
                    size_t oi = (size_t)(row0 + row) * H_ + ch;
                    outp[oi] = hv;
                    outp[(size_t)B_ * H_ + oi] = cn;
                } else {
                    hn[row * 256 + (((ch >> 4) ^ (row & 7)) << 4) + (ch & 15)] =
                        (char)__float2int_rn(hv * 127.0f);
                }
            }
        }

        asm volatile("s_waitcnt lgkmcnt(0)" ::: "memory");
        __builtin_amdgcn_s_barrier();
        cur ^= 1;
    }
#undef AFRAG8
}

extern "C" void kernel_launch(void* const* d_in, const int* in_sizes, int n_in,
                              void* d_out, int out_size, void* d_ws, size_t ws_size,
                              hipStream_t stream) {
    const float* x    = (const float*)d_in[0];
    const float* Wm   = (const float*)d_in[1];
    const float* Um   = (const float*)d_in[2];
    const float* bias = (const float*)d_in[3];

    // ws bytes: W2 @0 (512K) | U8 @512K (256K) | scq @768K (4K) |
    //           scd @772K (4K) | xz2 @776K (210 MB)      (ws = 400 MiB)
    ushort_t* W2  = (ushort_t*)d_ws;
    char*     U8  = (char*)d_ws + 524288;
    float*    scq = (float*)((char*)d_ws + 786432);
    float*    scd = (float*)((char*)d_ws + 790528);
    ushort_t* xz2 = (ushort_t*)((char*)d_ws + 794624);

    pack_w<<<128, 256, 0, stream>>>(Wm, W2);
    pack_scale<<<4, 256, 0, stream>>>(Um, scq, scd);
    pack_u8<<<64, 256, 0, stream>>>(Um, scq, U8);
    dim3 g1(T_, 32);
    xw_gemm<<<g1, 512, 0, stream>>>(x, bias, W2, xz2);
    lstm_rec<<<128, 512, 0, stream>>>(U8, scd, xz2, (float*)d_out, T_);
}

// Round 16
// 227.361 us; speedup vs baseline: 9.3436x; 1.2314x over previous
//
#include <hip/hip_runtime.h>

// LSTM recurrence, 50 steps. B=2048, T=50, F=256, H=256, gates i,f,g,o.
// Phase 0: pack W (bf16 frag order) + quantize U to int8 (per-column scale,
//          wave-parallel column max -- r15's pack_scale was a serial 256-load
//          chain per thread on a 4-block grid).
// Phase 1: xz = x@W + b, BM=64 tile (r15: 4:1 MFMA:B-load).
// Phase 2: persistent recurrence, 128 blocks x 16 rows, i8 U (r14 structure)
//          + XZ prefetched ONE STEP AHEAD (r16): XZ(t+1) issued after the
//          U streams (youngest in vmcnt queue -> stream waits vmcnt(16)/(8)
//          don't wait on it), consumed next epilogue with zero wait; the
//          lgkm-only barrier keeps it in flight across the step boundary.
//          r15 loaded XZ(t) at step top -> only ~700cy cover vs 400-2000cy
//          L3/HBM latency = exposed stall every step.

#define B_ 2048
#define T_ 50
#define F_ 256
#define H_ 256
#define NZ 1024      // 4H

typedef __attribute__((ext_vector_type(8))) short short8;
typedef __attribute__((ext_vector_type(4))) float f32x4;
typedef __attribute__((ext_vector_type(4))) int i32x4;
typedef unsigned short ushort_t;
typedef unsigned int uint_t;

__device__ __forceinline__ ushort_t f2bf(float f) {
    uint_t u = __float_as_uint(f);
    return (ushort_t)((u + 0x7FFFu + ((u >> 16) & 1u)) >> 16);
}
__device__ __forceinline__ uint_t pack2bf(float lo, float hi) {
    return (uint_t)f2bf(lo) | ((uint_t)f2bf(hi) << 16);
}
__device__ __forceinline__ float bf2f(ushort_t u) {
    return __uint_as_float(((uint_t)u) << 16);
}
__device__ __forceinline__ float sigm(float z) {
    return __builtin_amdgcn_rcpf(1.0f + __builtin_amdgcn_exp2f(z * -1.44269504f));
}
__device__ __forceinline__ float tanh_f(float z) {
    return 2.0f * __builtin_amdgcn_rcpf(1.0f + __builtin_amdgcn_exp2f(z * -2.88539008f)) - 1.0f;
}
__device__ __forceinline__ float xz_at(uint2 u, int j) {
    uint_t v = (j < 2) ? u.x : u.y;
    v = (j & 1) ? (v >> 16) : (v & 0xFFFFu);
    return bf2f((ushort_t)v);
}

// -------- pack W: fp32 [256][1024] -> bf16 frag-order panels ---------------
__global__ void pack_w(const float* __restrict__ Wm, ushort_t* __restrict__ W2) {
    int gid  = blockIdx.x * 256 + threadIdx.x;   // 32768 total
    int lane = gid & 63;
    int nf   = (gid >> 6) & 7;
    int w    = (gid >> 9) & 7;
    int kf   = (gid >> 12) & 7;
    int col = (nf >> 1) * 256 + w * 32 + (nf & 1) * 16 + (lane & 15);
    int kb  = kf * 32 + (lane >> 4) * 8;
    short8 v;
#pragma unroll
    for (int e = 0; e < 8; ++e)
        v[e] = (short)f2bf(Wm[(size_t)(kb + e) * NZ + col]);
    *(short8*)(W2 + ((((size_t)kf * 8 + w) * 8 + nf) * 64 + lane) * 8) = v;
}

// -------- U scales: per-column max, ONE WAVE PER COLUMN --------------------
__global__ void pack_scale(const float* __restrict__ Um,
                           float* __restrict__ scq, float* __restrict__ scd) {
    int j    = (blockIdx.x * 256 + threadIdx.x) >> 6;   // 0..1023 (wave id)
    int lane = threadIdx.x & 63;
    float mx = 0.f;
#pragma unroll
    for (int i = 0; i < H_ / 64; ++i)
        mx = fmaxf(mx, fabsf(Um[(size_t)(i * 64 + lane) * NZ + j]));
#pragma unroll
    for (int off = 32; off; off >>= 1)
        mx = fmaxf(mx, __shfl_down(mx, off));
    if (lane == 0) {
        scq[j] = (mx > 0.f) ? (127.0f / mx) : 0.f;
        scd[j] = mx * (1.0f / 16129.0f);      // mx/127^2
    }
}

// -------- pack U: fp32 -> i8 frag order for mfma_i32_16x16x64_i8 ----------
__global__ void pack_u8(const float* __restrict__ Um,
                        const float* __restrict__ scq, char* __restrict__ U8) {
    int gid  = blockIdx.x * 256 + threadIdx.x;   // 16384 total
    int lane = gid & 63;
    int nf   = (gid >> 6) & 7;
    int w    = (gid >> 9) & 7;
    int kf   = (gid >> 12) & 3;
    int col = (nf >> 1) * 256 + w * 32 + (nf & 1) * 16 + (lane & 15);
    int k0  = kf * 64 + (lane >> 4) * 16;
    float qs = scq[col];
    union { char c[16]; int4 v; } u;
#pragma unroll
    for (int e = 0; e < 16; ++e)
        u.c[e] = (char)__float2int_rn(Um[(size_t)(k0 + e) * NZ + col] * qs);
    *(int4*)(U8 + (((size_t)(kf * 8 + w) * 8 + nf) << 10) + (size_t)lane * 16) = u.v;
}

// -------- phase 1: xz[t] = x[:,t,:] @ W + b, BM=64 ------------------------
__global__ __launch_bounds__(512, 2) void xw_gemm(
    const float* __restrict__ x, const float* __restrict__ bias,
    const ushort_t* __restrict__ W2, ushort_t* __restrict__ xz2) {
    __shared__ __align__(16) ushort_t As[64 * 256];   // 32 KB, swizzled

    const int tid = threadIdx.x;
    const int t = blockIdx.x, rb = blockIdx.y, row0 = rb * 64;
    const int w = tid >> 6, lane = tid & 63, r16 = lane & 15, q = lane >> 4;

    {
        int sr = tid >> 4, sc = tid & 15;
#pragma unroll
        for (int rr = 0; rr < 64; rr += 32) {
            const float* xp = x + ((size_t)(row0 + rr + sr) * T_ + t) * F_ + sc * 16;
            float4 f0 = *(const float4*)(xp + 0);
            float4 f1 = *(const float4*)(xp + 4);
            float4 f2 = *(const float4*)(xp + 8);
            float4 f3 = *(const float4*)(xp + 12);
            uint4 u0 = {pack2bf(f0.x, f0.y), pack2bf(f0.z, f0.w),
                        pack2bf(f1.x, f1.y), pack2bf(f1.z, f1.w)};
            uint4 u1 = {pack2bf(f2.x, f2.y), pack2bf(f2.z, f2.w),
                        pack2bf(f3.x, f3.y), pack2bf(f3.z, f3.w)};
            int c0 = (2 * sc) ^ (sr & 7), c1 = (2 * sc + 1) ^ (sr & 7);
            *(uint4*)&As[(rr + sr) * 256 + c0 * 8] = u0;
            *(uint4*)&As[(rr + sr) * 256 + c1 * 8] = u1;
        }
    }
    float bcol[8];
#pragma unroll
    for (int nf = 0; nf < 8; ++nf)
        bcol[nf] = bias[(nf >> 1) * 256 + w * 32 + (nf & 1) * 16 + r16];
    __syncthreads();

    f32x4 acc[4][8];
#pragma unroll
    for (int m = 0; m < 4; ++m)
#pragma unroll
        for (int nf = 0; nf < 8; ++nf) acc[m][nf] = (f32x4){0.f, 0.f, 0.f, 0.f};
    short8 SB0[8], SB1[8];

#define LOADB(BUF, KF_)                                                       \
    _Pragma("unroll") for (int nf = 0; nf < 8; ++nf)                          \
        BUF[nf] = *(const short8*)(W2 +                                       \
            ((((size_t)(KF_) * 8 + w) * 8 + nf) * 64 + lane) * 8);

#define MF1(BUF, KF_)                                                         \
    do {                                                                      \
        _Pragma("unroll") for (int m = 0; m < 4; ++m) {                       \
            short8 a_ = *(const short8*)&As[(m * 16 + r16) * 256              \
                                            + (((KF_)*4 + q) ^ (r16 & 7)) * 8];\
            _Pragma("unroll") for (int nf = 0; nf < 8; ++nf)                  \
                acc[m][nf] = __builtin_amdgcn_mfma_f32_16x16x32_bf16(         \
                    a_, BUF[nf], acc[m][nf], 0, 0, 0);                        \
        }                                                                     \
    } while (0)

    LOADB(SB0, 0); LOADB(SB1, 1);
    MF1(SB0, 0); LOADB(SB0, 2);
    MF1(SB1, 1); LOADB(SB1, 3);
    MF1(SB0, 2); LOADB(SB0, 4);
    MF1(SB1, 3); LOADB(SB1, 5);
    MF1(SB0, 4); LOADB(SB0, 6);
    MF1(SB1, 5); LOADB(SB1, 7);
    MF1(SB0, 6);
    MF1(SB1, 7);

    uint2* outp = (uint2*)xz2;
#pragma unroll
    for (int m = 0; m < 4; ++m) {
        const size_t cb = (((size_t)t * 64 + (size_t)(rb * 2 + (m >> 1))) * 8 + w) * 16
                        + (size_t)(m & 1) * 8;
#pragma unroll
        for (int nf = 0; nf < 8; ++nf) {
            f32x4 a = acc[m][nf];
            float b = bcol[nf];
            uint2 o = {pack2bf(a[0] + b, a[1] + b), pack2bf(a[2] + b, a[3] + b)};
            outp[(cb + nf) * 64 + lane] = o;
        }
    }
#undef LOADB
#undef MF1
}

// -------- phase 2: persistent recurrence, i8 U + XZ prefetch --------------
__global__ __launch_bounds__(512, 1) void lstm_rec(
    const char* __restrict__ U8, const float* __restrict__ scd,
    const ushort_t* __restrict__ xz2, float* __restrict__ outp, int T) {
    __shared__ __align__(16) char UL[131072];     // U kf0,kf1 i8 (128 KB)
    __shared__ __align__(16) char hbc[2][4096];   // h i8 dbuf (2 x 4 KB)

    const int tid = threadIdx.x;
    const int rb = blockIdx.x, row0 = rb * 16;
    const int w = tid >> 6, lane = tid & 63, r16 = lane & 15, q = lane >> 4;

#pragma unroll
    for (int i = 0; i < 16; ++i) {
        int off = i * 8192 + tid * 16;
        __builtin_amdgcn_global_load_lds(
            (const __attribute__((address_space(1))) void*)(U8 + off),
            (__attribute__((address_space(3))) void*)(UL + off),
            16, 0, 0);
    }
    *(uint2*)&hbc[0][tid * 8] = (uint2){0, 0};

    float d[8];
#pragma unroll
    for (int nf = 0; nf < 8; ++nf)
        d[nf] = scd[(nf >> 1) * 256 + w * 32 + (nf & 1) * 16 + r16];

    const uint2* xzp = (const uint2*)xz2;
    const size_t cbconst = (((size_t)(rb >> 1)) * 8 + w) * 16 + (size_t)(rb & 1) * 8;
    const uint2* xzb = xzp + cbconst * 64 + lane;
    const size_t TSTRIDE = (size_t)8192 * 64;

#define AFRAG8(HP_, KF_)                                                      \
    (*(const i32x4*)&(HP_)[r16 * 256 + ((((KF_)*4 + q) ^ (r16 & 7)) << 4)])

    i32x4 acc[8];
    f32x4 creg[2];
    creg[0] = (f32x4){0.f, 0.f, 0.f, 0.f};
    creg[1] = (f32x4){0.f, 0.f, 0.f, 0.f};

    // XZ(0) loaded ahead of the loop; steady state: XZ(t+1) prefetched at
    // step t, one full step of cover.
    uint2 XZ[8];
#pragma unroll
    for (int k = 0; k < 8; ++k) XZ[k] = xzb[(size_t)k * 64];

    int cur = 0;
    __syncthreads();

#pragma clang loop unroll(disable)
    for (int t = 0; t < T; ++t) {
        const char* hc = hbc[cur];
        char* hn = hbc[cur ^ 1];

        // U streams FIRST (oldest in vmcnt queue -> their waits vmcnt(16)/(8)
        // never wait on the younger XZ prefetch)
        i32x4 S2[8], S3[8];
#pragma unroll
        for (int nf = 0; nf < 8; ++nf)
            S2[nf] = *(const i32x4*)(U8 + (((size_t)(2 * 8 + w) * 8 + nf) << 10)
                                     + (size_t)lane * 16);
#pragma unroll
        for (int nf = 0; nf < 8; ++nf)
            S3[nf] = *(const i32x4*)(U8 + (((size_t)(3 * 8 + w) * 8 + nf) << 10)
                                     + (size_t)lane * 16);
        // XZ(t+1) prefetch LAST; consumed next step's epilogue (full-step
        // cover). t=T-1 reads one tile past xz2 -- inside 400MiB ws, unused.
        uint2 XZn[8];
#pragma unroll
        for (int k = 0; k < 8; ++k)
            XZn[k] = xzb[(size_t)(t + 1) * TSTRIDE + (size_t)k * 64];

#pragma unroll
        for (int nf = 0; nf < 8; ++nf) acc[nf] = (i32x4){0, 0, 0, 0};

        __builtin_amdgcn_s_setprio(1);
#pragma unroll
        for (int kf = 0; kf < 2; ++kf) {
            i32x4 a = AFRAG8(hc, kf);
#pragma unroll
            for (int nf = 0; nf < 8; ++nf) {
                i32x4 b = *(const i32x4*)&UL[(((size_t)(kf * 8 + w) * 8 + nf) << 10)
                                             + (size_t)lane * 16];
                acc[nf] = __builtin_amdgcn_mfma_i32_16x16x64_i8(a, b, acc[nf], 0, 0, 0);
            }
        }
        {
            i32x4 a2 = AFRAG8(hc, 2);
#pragma unroll
            for (int nf = 0; nf < 8; ++nf)
                acc[nf] = __builtin_amdgcn_mfma_i32_16x16x64_i8(a2, S2[nf], acc[nf], 0, 0, 0);
            i32x4 a3 = AFRAG8(hc, 3);
#pragma unroll
            for (int nf = 0; nf < 8; ++nf)
                acc[nf] = __builtin_amdgcn_mfma_i32_16x16x64_i8(a3, S3[nf], acc[nf], 0, 0, 0);
        }
        __builtin_amdgcn_s_setprio(0);

        // epilogue: XZ(t) already in registers -- zero vmem wait
#pragma unroll
        for (int hf = 0; hf < 2; ++hf) {
#pragma unroll
            for (int j = 0; j < 4; ++j) {
                float zi = (float)acc[0 + hf][j] * d[0 + hf] + xz_at(XZ[0 + hf], j);
                float zf = (float)acc[2 + hf][j] * d[2 + hf] + xz_at(XZ[2 + hf], j);
                float zg = (float)acc[4 + hf][j] * d[4 + hf] + xz_at(XZ[4 + hf], j);
                float zo = (float)acc[6 + hf][j] * d[6 + hf] + xz_at(XZ[6 + hf], j);
                float ig = sigm(zi);
                float fg = sigm(zf);
                float gg = tanh_f(zg);
                float og = sigm(zo);
                float cn = fg * creg[hf][j] + ig * gg;
                float hv = og * tanh_f(cn);
                creg[hf][j] = cn;
                int row = q * 4 + j;
                int ch  = w * 32 + hf * 16 + r16;
                if (t == T_ - 1) {
                    size_t oi = (size_t)(row0 + row) * H_ + ch;
                    outp[oi] = hv;
                    outp[(size_t)B_ * H_ + oi] = cn;
                } else {
                    hn[row * 256 + (((ch >> 4) ^ (row & 7)) << 4) + (ch & 15)] =
                        (char)__float2int_rn(hv * 127.0f);
                }
            }
        }

        // carry prefetched XZ into next step (register rename, ~free)
#pragma unroll
        for (int k = 0; k < 8; ++k) XZ[k] = XZn[k];

        // raw barrier: drain LDS only; XZ(t+1) loads stay in flight
        asm volatile("s_waitcnt lgkmcnt(0)" ::: "memory");
        __builtin_amdgcn_s_barrier();
        cur ^= 1;
    }
#undef AFRAG8
}

extern "C" void kernel_launch(void* const* d_in, const int* in_sizes, int n_in,
                              void* d_out, int out_size, void* d_ws, size_t ws_size,
                              hipStream_t stream) {
    const float* x    = (const float*)d_in[0];
    const float* Wm   = (const float*)d_in[1];
    const float* Um   = (const float*)d_in[2];
    const float* bias = (const float*)d_in[3];

    // ws bytes: W2 @0 (512K) | U8 @512K (256K) | scq @768K (4K) |
    //           scd @772K (4K) | xz2 @776K (210 MB)      (ws = 400 MiB)
    ushort_t* W2  = (ushort_t*)d_ws;
    char*     U8  = (char*)d_ws + 524288;
    float*    scq = (float*)((char*)d_ws + 786432);
    float*    scd = (float*)((char*)d_ws + 790528);
    ushort_t* xz2 = (ushort_t*)((char*)d_ws + 794624);

    pack_w<<<128, 256, 0, stream>>>(Wm, W2);
    pack_scale<<<256, 256, 0, stream>>>(Um, scq, scd);
    pack_u8<<<64, 256, 0, stream>>>(Um, scq, U8);
    dim3 g1(T_, 32);
    xw_gemm<<<g1, 512, 0, stream>>>(x, bias, W2, xz2);
    lstm_rec<<<128, 512, 0, stream>>>(U8, scd, xz2, (float*)d_out, T_);
}